// Round 4
// baseline (189.832 us; speedup 1.0000x reference)
//
#include <hip/hip_runtime.h>

// QNStepTD: n-step TD loss.
//   target[b] = sum_{t<T} gamma^t*reward[t,b] + gamma^T*next_n_q[b,na[b]]*(1-done[b])
//   td[b]     = (q[b,a[b]] - target[b])^2 ; loss = mean(td*weight)
// d_out layout: [loss, td[0..B-1]]
//
// R4: T2 test (latency/MLP-bound hypothesis). R1/R2/R3 (atomic / divergent
// gather / coalesced LDS staging) all converge at ~63-65us = 2.7 TB/s
// effective. This version maximizes memory-level parallelism: 2 samples per
// thread, 2048 blocks (8 blocks/CU), launch_bounds(256,8) for 32 waves/CU,
// 11 independent loads issued before any use, no LDS, no barriers in the
// memory path. Gather loads only the 16B quarter-row containing the needed
// element; component chosen with 3 cndmasks in-register.

#define BLOCK 256

__global__ __launch_bounds__(BLOCK, 8) void qnstep_td_main(
    const float* __restrict__ q,
    const float* __restrict__ nq,
    const int*   __restrict__ act,
    const int*   __restrict__ nact,
    const float* __restrict__ rew,
    const int*   __restrict__ done,
    const float* __restrict__ w,
    const float* __restrict__ gamma_p,
    float*       __restrict__ out,      // out[1..B] = td
    float*       __restrict__ partial,  // per-block sums (d_ws)
    int B, int T)
{
    const int  g  = blockIdx.x * BLOCK + threadIdx.x;   // pair index
    const long long b0 = (long long)g * 2;              // first of 2 samples
    const float gamma = gamma_p[0];

    // ---- issue ALL independent loads up front ----
    const int2   a2  = ((const int2*)act)[g];
    const int2   na2 = ((const int2*)nact)[g];
    const int2   d2  = ((const int2*)done)[g];
    const float2 w2  = ((const float2*)w)[g];

    // gather: 16B quarter-row containing the wanted element (N==16 fast path)
    const float4 qv0  = *(const float4*)(q  + (b0 << 4)       + ((long long)(a2.x  >> 2) << 2));
    const float4 qv1  = *(const float4*)(q  + ((b0 + 1) << 4) + ((long long)(a2.y  >> 2) << 2));
    const float4 nqv0 = *(const float4*)(nq + (b0 << 4)       + ((long long)(na2.x >> 2) << 2));
    const float4 nqv1 = *(const float4*)(nq + ((b0 + 1) << 4) + ((long long)(na2.y >> 2) << 2));

    float2 r[8];
    #pragma unroll 8
    for (int t = 0; t < T; ++t)
        r[t] = ((const float2*)(rew + (long long)t * B))[g];

    // ---- compute ----
    float t0 = 0.f, t1 = 0.f, f = 1.0f;
    #pragma unroll 8
    for (int t = 0; t < T; ++t) {
        t0 += f * r[t].x; t1 += f * r[t].y;
        f *= gamma;
    }

    // in-register component select (a&3)
    const int c0 = a2.x & 3, c1 = a2.y & 3, c2 = na2.x & 3, c3 = na2.y & 3;
    const float qa0  = (c0 < 2) ? (c0 == 0 ? qv0.x  : qv0.y)  : (c0 == 2 ? qv0.z  : qv0.w);
    const float qa1  = (c1 < 2) ? (c1 == 0 ? qv1.x  : qv1.y)  : (c1 == 2 ? qv1.z  : qv1.w);
    const float nqa0 = (c2 < 2) ? (c2 == 0 ? nqv0.x : nqv0.y) : (c2 == 2 ? nqv0.z : nqv0.w);
    const float nqa1 = (c3 < 2) ? (c3 == 0 ? nqv1.x : nqv1.y) : (c3 == 2 ? nqv1.z : nqv1.w);

    t0 += f * nqa0 * (d2.x ? 0.f : 1.f);
    t1 += f * nqa1 * (d2.y ? 0.f : 1.f);

    const float e0 = qa0 - t0, e1 = qa1 - t1;
    const float td0 = e0 * e0, td1 = e1 * e1;

    out[1 + b0]     = td0;
    out[1 + b0 + 1] = td1;

    float val = td0 * w2.x + td1 * w2.y;

    // ---- block reduction -> partial[blk] ----
    #pragma unroll
    for (int off = 32; off > 0; off >>= 1)
        val += __shfl_down(val, off, 64);

    __shared__ float ssum[BLOCK / 64];
    if ((threadIdx.x & 63) == 0) ssum[threadIdx.x >> 6] = val;
    __syncthreads();
    if (threadIdx.x == 0) {
        float s = 0.f;
        #pragma unroll
        for (int i = 0; i < BLOCK / 64; ++i) s += ssum[i];
        partial[blockIdx.x] = s;
    }
}

// generic fallback (any N, any B)
__global__ __launch_bounds__(256) void qnstep_td_generic(
    const float* __restrict__ q, const float* __restrict__ nq,
    const int* __restrict__ act, const int* __restrict__ nact,
    const float* __restrict__ rew, const int* __restrict__ done,
    const float* __restrict__ w, const float* __restrict__ gamma_p,
    float* __restrict__ out, float* __restrict__ partial,
    int B, int N, int T)
{
    const int b = blockIdx.x * blockDim.x + threadIdx.x;
    const float gamma = gamma_p[0];
    float val = 0.0f;
    if (b < B) {
        float f = 1.0f, tgt = 0.0f;
        for (int t = 0; t < T; ++t) { tgt += f * rew[(long long)t * B + b]; f *= gamma; }
        const float nd = (done[b] != 0) ? 0.f : 1.f;
        tgt += f * nq[(long long)b * N + nact[b]] * nd;
        const float d = q[(long long)b * N + act[b]] - tgt;
        const float td = d * d;
        out[1 + b] = td;
        val = td * w[b];
    }
    #pragma unroll
    for (int off = 32; off > 0; off >>= 1) val += __shfl_down(val, off, 64);
    __shared__ float ssum[4];
    if ((threadIdx.x & 63) == 0) ssum[threadIdx.x >> 6] = val;
    __syncthreads();
    if (threadIdx.x == 0)
        partial[blockIdx.x] = ssum[0] + ssum[1] + ssum[2] + ssum[3];
}

__global__ __launch_bounds__(1024) void qnstep_td_reduce(
    const float* __restrict__ partial, float* __restrict__ out,
    int n, float invB)
{
    const int tid = threadIdx.x;
    float v = 0.0f;
    for (int i = tid; i < n; i += 1024) v += partial[i];

    #pragma unroll
    for (int off = 32; off > 0; off >>= 1)
        v += __shfl_down(v, off, 64);

    __shared__ float ssum[16];
    if ((tid & 63) == 0) ssum[tid >> 6] = v;
    __syncthreads();

    if (tid == 0) {
        float s = 0.0f;
        #pragma unroll
        for (int i = 0; i < 16; ++i) s += ssum[i];
        out[0] = s * invB;  // overwrites poison
    }
}

extern "C" void kernel_launch(void* const* d_in, const int* in_sizes, int n_in,
                              void* d_out, int out_size, void* d_ws, size_t ws_size,
                              hipStream_t stream) {
    const float* q     = (const float*)d_in[0];
    const float* nq    = (const float*)d_in[1];
    const int*   act   = (const int*)d_in[2];
    const int*   nact  = (const int*)d_in[3];
    const float* rew   = (const float*)d_in[4];
    const int*   done  = (const int*)d_in[5];
    const float* w     = (const float*)d_in[6];
    const float* gamma = (const float*)d_in[7];

    const int B = in_sizes[2];            // action is (B,)
    const int N = in_sizes[0] / B;        // q is (B, N)
    const int T = in_sizes[4] / B;        // reward is (T, B)

    float* out     = (float*)d_out;
    float* partial = (float*)d_ws;

    if (N == 16 && (B % (BLOCK * 2)) == 0 && T <= 8) {
        const int grid = B / (BLOCK * 2);   // 2048 for B=1M
        qnstep_td_main<<<grid, BLOCK, 0, stream>>>(
            q, nq, act, nact, rew, done, w, gamma, out, partial, B, T);
        qnstep_td_reduce<<<1, 1024, 0, stream>>>(partial, out, grid, 1.0f / (float)B);
    } else {
        const int grid = (B + 255) / 256;
        qnstep_td_generic<<<grid, 256, 0, stream>>>(
            q, nq, act, nact, rew, done, w, gamma, out, partial, B, N, T);
        qnstep_td_reduce<<<1, 1024, 0, stream>>>(partial, out, grid, 1.0f / (float)B);
    }
}

// Round 5
// 187.693 us; speedup vs baseline: 1.0114x; 1.0114x over previous
//
#include <hip/hip_runtime.h>

// QNStepTD: n-step TD loss.
//   target[b] = sum_{t<T} gamma^t*reward[t,b] + gamma^T*next_n_q[b,na[b]]*(1-done[b])
//   td[b]     = (q[b,a[b]] - target[b])^2 ; loss = mean(td*weight)
// d_out layout: [loss, td[0..B-1]]
//
// R5: persistent software-pipelined kernel. R1-R4 (atomic / divergent /
// LDS-staged / burst-MLP) all converge at ~63-66us = 1.4 TB/s HBM with
// FETCH(84MB) < logical(164MB): not BW-bound, latency x outstanding-miss
// bound, and per-wave one-shot load bursts can't sustain the in-flight line
// count. This kernel: 512 persistent blocks (2/CU), 4 iters/thread, 3-deep
// pipeline (scalars 2 ahead, index-dependent gathers 1 ahead, compute on
// oldest) so VMEM stays occupied for the kernel's whole life. Loss via 512
// per-block atomics (overlapped) + 4B memset node; no reduce kernel.

#define BLOCK 256
#define GRID  512

struct SStage {                 // streamed per-pair loads
    int2   a, na, d;
    float2 w;
    float2 r0, r1, r2, r3, r4;  // T=5 reward rows
};
struct GStage {                 // gathered quarter-rows (16B granules)
    float4 q0, q1, n0, n1;
};

__device__ __forceinline__ SStage load_s(
    int g, const int* __restrict__ act, const int* __restrict__ nact,
    const int* __restrict__ done, const float* __restrict__ w,
    const float* __restrict__ rew, int PB)
{
    SStage s;
    s.a  = ((const int2*)act)[g];
    s.na = ((const int2*)nact)[g];
    s.d  = ((const int2*)done)[g];
    s.w  = ((const float2*)w)[g];
    const float2* r = (const float2*)rew;
    s.r0 = r[g];
    s.r1 = r[g + PB];
    s.r2 = r[g + 2 * PB];
    s.r3 = r[g + 3 * PB];
    s.r4 = r[g + 4 * PB];
    return s;
}

__device__ __forceinline__ GStage load_g(
    const SStage& s, int g, const float* __restrict__ q,
    const float* __restrict__ nq)
{
    GStage o;
    const long long b0 = (long long)g * 2;
    o.q0 = *(const float4*)(q  + (b0 << 4)       + ((s.a.x  >> 2) << 2));
    o.q1 = *(const float4*)(q  + ((b0 + 1) << 4) + ((s.a.y  >> 2) << 2));
    o.n0 = *(const float4*)(nq + (b0 << 4)       + ((s.na.x >> 2) << 2));
    o.n1 = *(const float4*)(nq + ((b0 + 1) << 4) + ((s.na.y >> 2) << 2));
    return o;
}

__device__ __forceinline__ float sel4(const float4& v, int c) {
    const float lo = (c & 1) ? v.y : v.x;
    const float hi = (c & 1) ? v.w : v.z;
    return (c & 2) ? hi : lo;
}

__global__ __launch_bounds__(BLOCK, 2) void qnstep_persist(
    const float* __restrict__ q,
    const float* __restrict__ nq,
    const int*   __restrict__ act,
    const int*   __restrict__ nact,
    const float* __restrict__ rew,
    const int*   __restrict__ done,
    const float* __restrict__ w,
    const float* __restrict__ gamma_p,
    float*       __restrict__ out,     // out[0]=loss (pre-zeroed), out[1..B]=td
    int B, int iters, float invB)
{
    const int stride = GRID * BLOCK;
    const int PB = B >> 1;
    int g = blockIdx.x * BLOCK + threadIdx.x;   // pair index
    const float gamma = gamma_p[0];
    const float g5 = gamma * gamma * gamma * gamma * gamma;

    // pipeline prologue (iters >= 2 guaranteed by launcher)
    SStage s0  = load_s(g, act, nact, done, w, rew, PB);
    SStage s1  = load_s(g + stride, act, nact, done, w, rew, PB);
    GStage gg0 = load_g(s0, g, q, nq);

    float val = 0.0f;
    for (int i = 0; i < iters; ++i) {
        SStage s2  = {};
        GStage gg1 = {};
        if (i + 2 < iters) s2  = load_s(g + 2 * stride, act, nact, done, w, rew, PB);
        if (i + 1 < iters) gg1 = load_g(s1, g + stride, q, nq);

        // ---- compute on oldest stage ----
        const long long b0 = (long long)g * 2;
        float t0 = s0.r0.x + gamma * (s0.r1.x + gamma * (s0.r2.x + gamma * (s0.r3.x + gamma * s0.r4.x)));
        float t1 = s0.r0.y + gamma * (s0.r1.y + gamma * (s0.r2.y + gamma * (s0.r3.y + gamma * s0.r4.y)));

        const float qa0  = sel4(gg0.q0, s0.a.x  & 3);
        const float qa1  = sel4(gg0.q1, s0.a.y  & 3);
        const float nqa0 = sel4(gg0.n0, s0.na.x & 3);
        const float nqa1 = sel4(gg0.n1, s0.na.y & 3);

        t0 += g5 * nqa0 * (s0.d.x ? 0.f : 1.f);
        t1 += g5 * nqa1 * (s0.d.y ? 0.f : 1.f);

        const float e0 = qa0 - t0, e1 = qa1 - t1;
        const float td0 = e0 * e0, td1 = e1 * e1;
        out[1 + b0]     = td0;
        out[2 + b0]     = td1;
        val += td0 * s0.w.x + td1 * s0.w.y;

        // rotate pipeline
        s0 = s1; s1 = s2; gg0 = gg1;
        g += stride;
    }

    // ---- block reduction -> one atomic ----
    #pragma unroll
    for (int off = 32; off > 0; off >>= 1)
        val += __shfl_down(val, off, 64);

    __shared__ float ssum[BLOCK / 64];
    if ((threadIdx.x & 63) == 0) ssum[threadIdx.x >> 6] = val;
    __syncthreads();
    if (threadIdx.x == 0) {
        float s = 0.f;
        #pragma unroll
        for (int i = 0; i < BLOCK / 64; ++i) s += ssum[i];
        atomicAdd(out, s * invB);   // 512 atomics total, overlapped
    }
}

// generic fallback (any N/B/T)
__global__ __launch_bounds__(256) void qnstep_td_generic(
    const float* __restrict__ q, const float* __restrict__ nq,
    const int* __restrict__ act, const int* __restrict__ nact,
    const float* __restrict__ rew, const int* __restrict__ done,
    const float* __restrict__ w, const float* __restrict__ gamma_p,
    float* __restrict__ out, int B, int N, int T, float invB)
{
    const int b = blockIdx.x * blockDim.x + threadIdx.x;
    const float gamma = gamma_p[0];
    float val = 0.0f;
    if (b < B) {
        float f = 1.0f, tgt = 0.0f;
        for (int t = 0; t < T; ++t) { tgt += f * rew[(long long)t * B + b]; f *= gamma; }
        const float nd = (done[b] != 0) ? 0.f : 1.f;
        tgt += f * nq[(long long)b * N + nact[b]] * nd;
        const float d = q[(long long)b * N + act[b]] - tgt;
        const float td = d * d;
        out[1 + b] = td;
        val = td * w[b];
    }
    #pragma unroll
    for (int off = 32; off > 0; off >>= 1) val += __shfl_down(val, off, 64);
    __shared__ float ssum[4];
    if ((threadIdx.x & 63) == 0) ssum[threadIdx.x >> 6] = val;
    __syncthreads();
    if (threadIdx.x == 0)
        atomicAdd(out, (ssum[0] + ssum[1] + ssum[2] + ssum[3]) * invB);
}

extern "C" void kernel_launch(void* const* d_in, const int* in_sizes, int n_in,
                              void* d_out, int out_size, void* d_ws, size_t ws_size,
                              hipStream_t stream) {
    const float* q     = (const float*)d_in[0];
    const float* nq    = (const float*)d_in[1];
    const int*   act   = (const int*)d_in[2];
    const int*   nact  = (const int*)d_in[3];
    const float* rew   = (const float*)d_in[4];
    const int*   done  = (const int*)d_in[5];
    const float* w     = (const float*)d_in[6];
    const float* gamma = (const float*)d_in[7];

    const int B = in_sizes[2];            // action is (B,)
    const int N = in_sizes[0] / B;        // q is (B, N)
    const int T = in_sizes[4] / B;        // reward is (T, B)

    float* out = (float*)d_out;

    // zero the loss slot (harness poisons d_out with 0xAA)
    hipMemsetAsync(out, 0, sizeof(float), stream);

    const int chunk = GRID * BLOCK * 2;   // samples per sweep
    const float invB = 1.0f / (float)B;

    if (N == 16 && T == 5 && (B % chunk) == 0 && (B / chunk) >= 2) {
        const int iters = B / chunk;      // 4 for B=1M
        qnstep_persist<<<GRID, BLOCK, 0, stream>>>(
            q, nq, act, nact, rew, done, w, gamma, out, B, iters, invB);
    } else {
        const int grid = (B + 255) / 256;
        qnstep_td_generic<<<grid, 256, 0, stream>>>(
            q, nq, act, nact, rew, done, w, gamma, out, B, N, T, invB);
    }
}